// Round 1
// baseline (1049.253 us; speedup 1.0000x reference)
//
#include <hip/hip_runtime.h>
#include <math.h>

#define N_ROWS 131072
#define C_CLS  1000
#define IGNORE_IDX (-100)

static constexpr float EPSF = 0.1f;
static constexpr float NEG_CONSTF = 0.5945275813408382f;
static constexpr float POS_DENOM  = 0.32447699714575207f; // POS_CONST = 1/this
static constexpr float L2E = 1.4426950408889634f;  // log2(e)
static constexpr float LN2 = 0.6931471805599453f;  // ln(2)

// acc[0] = sum over rows of (C*logZ - sum_x)
// acc[1] = sum over valid rows of picked (= x[target] - logZ)
// acc[2] = valid count
// acc[3] = correction sum (rows < C only)
__global__ __launch_bounds__(256) void lsce_main(
    const float* __restrict__ out, const int* __restrict__ tgt,
    float* __restrict__ acc, int rows_per_wave)
{
    const int lane = threadIdx.x & 63;
    const int wave = blockIdx.x * (blockDim.x >> 6) + (threadIdx.x >> 6);
    const int row0 = wave * rows_per_wave;

    float loss_acc = 0.f, nll_acc = 0.f, corr_acc = 0.f;
    float valid_cnt = 0.f;

    for (int r = 0; r < rows_per_wave; ++r) {
        const int row = row0 + r;
        if (row >= N_ROWS) break;
        const float* rp = out + (size_t)row * C_CLS;
        const int t = tgt[row];
        // wave-uniform broadcast load of the target element (issued early)
        float tv = (t >= 0 && t < C_CLS) ? rp[t] : 0.f;

        // 250 float4 per row; lane reads idx = lane + 64*k, k=0..3 (masked at >=250)
        float v[16];
        #pragma unroll
        for (int k = 0; k < 4; ++k) {
            const int idx = lane + 64 * k;
            float4 f;
            if (idx < 250) f = ((const float4*)rp)[idx];
            else { f.x = -INFINITY; f.y = -INFINITY; f.z = -INFINITY; f.w = -INFINITY; }
            v[4*k+0] = f.x; v[4*k+1] = f.y; v[4*k+2] = f.z; v[4*k+3] = f.w;
        }

        // local max / first-occurrence argmax / plain sum
        float m = -INFINITY; int amax = 0; float sum = 0.f;
        #pragma unroll
        for (int k = 0; k < 4; ++k) {
            #pragma unroll
            for (int c2 = 0; c2 < 4; ++c2) {
                const float x = v[4*k + c2];
                if (x > m) { m = x; amax = 4 * (lane + 64 * k) + c2; }
                sum += (x == -INFINITY) ? 0.f : x;
            }
        }
        // local sum of exp(x - m); masked entries give exp2(-inf) = 0
        float se = 0.f;
        #pragma unroll
        for (int j = 0; j < 16; ++j) se += exp2f((v[j] - m) * L2E);

        // 64-lane butterfly: combine (m, se), (amax min-index tiebreak), (sum)
        #pragma unroll
        for (int off = 1; off < 64; off <<= 1) {
            const float m2  = __shfl_xor(m, off);
            const float s2  = __shfl_xor(se, off);
            const int   a2  = __shfl_xor(amax, off);
            sum += __shfl_xor(sum, off);
            const bool take = (m2 > m) || (m2 == m && a2 < amax);
            const float M = fmaxf(m2, m);
            se = se * exp2f((m - M) * L2E) + s2 * exp2f((m2 - M) * L2E);
            amax = take ? a2 : amax;
            m = M;
        }

        const float logZ = m + log2f(se) * LN2;
        loss_acc += (float)C_CLS * logZ - sum;
        if (t != IGNORE_IDX) { nll_acc += tv - logZ; valid_cnt += 1.f; }
        if (row < C_CLS) {
            const int lt = amax + t;
            const int ad = (amax > t) ? (amax - t) : (t - amax);
            float pe = 0.f;
            if (lt >= 2)                 pe = EPSF / POS_DENOM;
            else if (lt == 1 && ad != 1) pe = -EPSF * NEG_CONSTF;
            corr_acc += pe;
        }
    }

    if (lane == 0) {
        atomicAdd(&acc[0], loss_acc);
        atomicAdd(&acc[1], nll_acc);
        atomicAdd(&acc[2], valid_cnt);
        atomicAdd(&acc[3], corr_acc);
    }
}

__global__ void lsce_final(const float* __restrict__ acc, float* __restrict__ out)
{
    const float loss = acc[0] / (float)N_ROWS;
    const float vc   = fmaxf(acc[2], 1.f);
    const float nll  = -(acc[1] / vc);
    const float corr = acc[3] / (float)C_CLS;
    out[0] = loss * EPSF / (float)C_CLS + (1.f - EPSF) * nll + corr;
}

extern "C" void kernel_launch(void* const* d_in, const int* in_sizes, int n_in,
                              void* d_out, int out_size, void* d_ws, size_t ws_size,
                              hipStream_t stream)
{
    const float* output = (const float*)d_in[0];
    const int*   target = (const int*)d_in[1];
    float* acc = (float*)d_ws;      // 4 floats of scratch
    float* outp = (float*)d_out;

    hipMemsetAsync(acc, 0, 4 * sizeof(float), stream);

    const int blocks = 2048;               // 4 waves each -> 8192 waves
    const int waves  = blocks * 4;
    const int rows_per_wave = (N_ROWS + waves - 1) / waves;   // 16

    lsce_main<<<blocks, 256, 0, stream>>>(output, target, acc, rows_per_wave);
    lsce_final<<<1, 1, 0, stream>>>(acc, outp);
}